// Round 1
// baseline (316.441 us; speedup 1.0000x reference)
//
#include <hip/hip_runtime.h>
#include <cstddef>

#define HD 8
#define C2 16
#define HH 28
#define WW 28
#define BB 16
#define SP (HH*WW)           // 784
#define FEAT (HD*SP)         // 6272
#define FEAT2 (C2*SP)        // 12544

#define TILE_ROWS 2
#define NT (HH/TILE_ROWS)    // 14
#define BLK_PER_NODE (BB*NT) // 224

__device__ __forceinline__ float sigf(float x) { return 1.0f / (1.0f + expf(-x)); }

struct GruArgs {
    const float* x;        // (B,8,784) or null (=> zeros)
    const float* h;        // (B,8,784) or null (=> zeros)
    const float* td;       // full (B,16,784) or null
    const float* td_bias;  // (12544) bias-reshape path
    const int*   td_flag;  // if set: *flag==0 -> bias path, else td path
    const float* gw;       // (16,16,3,3)
    const float* gb;       // (16)
    const float* cw;       // (8,16,3,3)
    const float* cb;       // (8)
    float*       hout;     // (B,8,784)
    int*         out_flag; // optional: set to 1 if any output nonzero
    float        xscale;
};

// Fused ConvGRU cell. Block = (node, image, 2-row tile). 256 threads.
__global__ __launch_bounds__(256)
void gru_kernel(GruArgs a0, GruArgs a1, GruArgs a2) {
    const int tid   = threadIdx.x;
    const int node  = blockIdx.x / BLK_PER_NODE;
    const int local = blockIdx.x % BLK_PER_NODE;
    const int bi    = local / NT;
    const int r0    = (local % NT) * TILE_ROWS;

    GruArgs a = a0;
    if (node == 1) a = a1;
    else if (node == 2) a = a2;

    __shared__ float s_gw[C2*C2*9];                 // 2304 f
    __shared__ float s_cw[HD*C2*9];                 // 1152 f
    __shared__ float s_gb[C2];
    __shared__ float s_cb[HD];
    __shared__ float s_comb[C2][TILE_ROWS+4][32];   // rows r0-2..r0+3, cols -2..29
    __shared__ float s_cin[C2][TILE_ROWS+2][32];    // rows r0-1..r0+2, cols -1..28(+pad)

    const bool use_bias = a.td_flag ? (*a.td_flag == 0) : (a.td == nullptr);

    for (int i = tid; i < C2*C2*9; i += 256) s_gw[i] = a.gw[i];
    for (int i = tid; i < HD*C2*9; i += 256) s_cw[i] = a.cw[i];
    if (tid < C2) s_gb[tid] = a.gb[tid];
    if (tid < HD) s_cb[tid] = a.cb[tid];

    // Phase A1: combined = concat([xscale*x, h]) * sigmoid(td), zero-padded tile
    for (int i = tid; i < C2*(TILE_ROWS+4)*32; i += 256) {
        int cidx = i & 31;
        int ridx = (i >> 5) % (TILE_ROWS+4);
        int c    = i / ((TILE_ROWS+4)*32);
        int row = r0 - 2 + ridx;
        int col = cidx - 2;
        float v = 0.0f;
        if (row >= 0 && row < HH && col >= 0 && col < WW) {
            float base = 0.0f;
            if (c < HD) { if (a.x) base = a.xscale * a.x[((size_t)bi*HD + c)*SP + row*WW + col]; }
            else        { if (a.h) base = a.h[((size_t)bi*HD + (c-HD))*SP + row*WW + col]; }
            if (base != 0.0f) {
                float tdv = use_bias ? a.td_bias[c*SP + row*WW + col]
                                     : a.td[((size_t)bi*C2 + c)*SP + row*WW + col];
                v = base * sigf(tdv);
            }
        }
        s_comb[c][ridx][cidx] = v;
    }

    // Phase A2: cand-input channels 0..7 = xscale * x (unmodulated)
    for (int i = tid; i < HD*(TILE_ROWS+2)*32; i += 256) {
        int cidx = i & 31;
        int ridx = (i >> 5) % (TILE_ROWS+2);
        int c    = i / ((TILE_ROWS+2)*32);
        int row = r0 - 1 + ridx;
        int col = cidx - 1;
        float v = 0.0f;
        if (a.x && row >= 0 && row < HH && col >= 0 && col < WW)
            v = a.xscale * a.x[((size_t)bi*HD + c)*SP + row*WW + col];
        s_cin[c][ridx][cidx] = v;
    }

    __syncthreads();

    // Phase B: r gates at rows r0-1..r0+2 (4) x cols -1..28 (30) x 8ch (2 halves)
    if (tid < (TILE_ROWS+2)*30*2) {
        int half  = tid & 1;
        int pos   = tid >> 1;
        int ridx2 = pos / 30;        // 0..3 ; row = r0-1+ridx2
        int cp    = pos % 30;        // col = cp-1
        float acc0 = s_gb[half*4+0], acc1 = s_gb[half*4+1],
              acc2 = s_gb[half*4+2], acc3 = s_gb[half*4+3];
        for (int ic = 0; ic < C2; ++ic) {
            float cv[3][3];
            #pragma unroll
            for (int dy = 0; dy < 3; ++dy)
                #pragma unroll
                for (int dx = 0; dx < 3; ++dx)
                    cv[dy][dx] = s_comb[ic][ridx2+dy][cp+dx];
            const float* wp = &s_gw[(half*4*C2 + ic)*9];
            #pragma unroll
            for (int dy = 0; dy < 3; ++dy)
                #pragma unroll
                for (int dx = 0; dx < 3; ++dx) {
                    float cvv = cv[dy][dx];
                    acc0 += cvv * wp[0*C2*9 + dy*3+dx];
                    acc1 += cvv * wp[1*C2*9 + dy*3+dx];
                    acc2 += cvv * wp[2*C2*9 + dy*3+dx];
                    acc3 += cvv * wp[3*C2*9 + dy*3+dx];
                }
        }
        int row = r0 - 1 + ridx2;
        int col = cp - 1;
        bool inb = (row >= 0 && row < HH && col >= 0 && col < WW);
        float av[4] = {acc0, acc1, acc2, acc3};
        #pragma unroll
        for (int o = 0; o < 4; ++o) {
            int ch = half*4 + o;
            float hv = 0.0f;
            if (a.h && inb) hv = a.h[((size_t)bi*HD + ch)*SP + row*WW + col];
            s_cin[HD + ch][ridx2][cp] = sigf(av[o]) * hv;
        }
    }

    __syncthreads();

    // Phase C: u gate + cand conv + blend, 2 rows x 28 cols x 8 ch
    bool nz = false;
    for (int item = tid; item < TILE_ROWS*WW*HD; item += 256) {
        int c   = item / (TILE_ROWS*WW);
        int rem = item % (TILE_ROWS*WW);
        int rr  = rem / WW;
        int col = rem % WW;
        float uacc = s_gb[HD + c];
        float cacc = s_cb[c];
        for (int ic = 0; ic < C2; ++ic) {
            const float* uwp = &s_gw[((HD + c)*C2 + ic)*9];
            const float* cwp = &s_cw[(c*C2 + ic)*9];
            #pragma unroll
            for (int dy = 0; dy < 3; ++dy)
                #pragma unroll
                for (int dx = 0; dx < 3; ++dx) {
                    uacc += s_comb[ic][rr+1+dy][col+1+dx] * uwp[dy*3+dx];
                    cacc += s_cin[ic][rr+dy][col+dx]      * cwp[dy*3+dx];
                }
        }
        float u    = sigf(uacc);
        float cand = tanhf(cacc);
        int row = r0 + rr;
        size_t oidx = ((size_t)bi*HD + c)*SP + row*WW + col;
        float hv = a.h ? a.h[oidx] : 0.0f;
        float outv = (1.0f - u) * hv + u * cand;
        a.hout[oidx] = outv;
        nz |= (outv != 0.0f);
    }

    if (a.out_flag) {
        unsigned long long m = __ballot(nz);
        if ((tid & 63) == 0 && m) atomicOr(a.out_flag, 1);
    }
}

__global__ __launch_bounds__(256)
void input_conv_kernel(const float* __restrict__ in, const float* __restrict__ w,
                       const float* __restrict__ b, float* __restrict__ out) {
    int idx = blockIdx.x * blockDim.x + threadIdx.x;   // over B*8*784
    if (idx >= BB*HD*SP) return;
    int col = idx % WW;
    int row = (idx / WW) % HH;
    int oc  = (idx / SP) % HD;
    int bi  = idx / (HD*SP);
    float acc = b[oc];
    for (int c = 0; c < 3; ++c)
        #pragma unroll
        for (int dy = 0; dy < 3; ++dy) {
            int rr = row + dy - 1;
            if (rr < 0 || rr >= HH) continue;
            #pragma unroll
            for (int dx = 0; dx < 3; ++dx) {
                int cc = col + dx - 1;
                if (cc < 0 || cc >= WW) continue;
                acc += in[((size_t)bi*3 + c)*SP + rr*WW + cc] * w[((oc*3 + c)*3 + dy)*3 + dx];
            }
        }
    out[idx] = acc;
}

// Flag-gated dual td projection: out[b,:] = bias + (scale*hin[b,:]) @ w^T
// Skipped entirely (consumer uses bias path) when the input tensor is all-zero.
__global__ __launch_bounds__(256)
void td_gemm_kernel(const float* __restrict__ h1, const float* __restrict__ w0,
                    const float* __restrict__ b0, float* __restrict__ out0,
                    const float* __restrict__ h2, const float* __restrict__ w1,
                    const float* __restrict__ b1, float* __restrict__ out1,
                    const int* __restrict__ flags) {
    int node = blockIdx.x / 49;
    if (flags[node] == 0) return;
    int j = (blockIdx.x % 49) * 256 + threadIdx.x;
    if (j >= FEAT2) return;
    const float* hin  = node ? h2 : h1;
    const float* w    = node ? w1 : w0;
    const float* bias = node ? b1 : b0;
    float* out        = node ? out1 : out0;
    float scale       = node ? 0.5f : 0.6f;
    float acc[BB];
    #pragma unroll
    for (int q = 0; q < BB; ++q) acc[q] = 0.0f;
    const float* wr = w + (size_t)j * FEAT;
    for (int k = 0; k < FEAT; ++k) {
        float wv = wr[k];
        #pragma unroll
        for (int q = 0; q < BB; ++q) acc[q] += (scale * hin[(size_t)q*FEAT + k]) * wv;
    }
    #pragma unroll
    for (int q = 0; q < BB; ++q) out[(size_t)q*FEAT2 + j] = acc[q] + bias[j];
}

__global__ __launch_bounds__(256)
void fc1_kernel(const float* __restrict__ in, const float* __restrict__ w,
                const float* __restrict__ b, float* __restrict__ out) {
    int j    = blockIdx.x;          // 0..99
    int wave = threadIdx.x >> 6;    // 0..3, each handles 4 batch rows
    int lane = threadIdx.x & 63;
    float acc[4] = {0.f, 0.f, 0.f, 0.f};
    const float* wr = w + (size_t)j * FEAT;
    for (int k = lane; k < FEAT; k += 64) {
        float wv = wr[k];
        #pragma unroll
        for (int q = 0; q < 4; ++q) {
            float v = in[(size_t)(wave*4+q)*FEAT + k];
            acc[q] += fmaxf(v, 0.0f) * wv;
        }
    }
    #pragma unroll
    for (int off = 32; off > 0; off >>= 1)
        #pragma unroll
        for (int q = 0; q < 4; ++q)
            acc[q] += __shfl_down(acc[q], off);
    if (lane == 0) {
        #pragma unroll
        for (int q = 0; q < 4; ++q)
            out[(size_t)(wave*4+q)*100 + j] = acc[q] + b[j];
    }
}

__global__ __launch_bounds__(256)
void fc2_kernel(const float* __restrict__ p1, const float* __restrict__ w,
                const float* __restrict__ b, float* __restrict__ out) {
    int t = threadIdx.x;
    if (t >= BB*10) return;
    int bi = t / 10, j = t % 10;
    float acc = b[j];
    for (int k = 0; k < 100; ++k)
        acc += fmaxf(p1[bi*100 + k], 0.0f) * w[j*100 + k];
    out[bi*10 + j] = acc;
}

extern "C" void kernel_launch(void* const* d_in, const int* in_sizes, int n_in,
                              void* d_out, int out_size, void* d_ws, size_t ws_size,
                              hipStream_t stream) {
    const float* input_tensor = (const float*)d_in[0];
    const float* topdown      = (const float*)d_in[1];
    const float* icw  = (const float*)d_in[2];
    const float* icb  = (const float*)d_in[3];
    const float* gates_w = (const float*)d_in[4];
    const float* gates_b = (const float*)d_in[5];
    const float* can_w   = (const float*)d_in[6];
    const float* can_b   = (const float*)d_in[7];
    const float* td_w0 = (const float*)d_in[8];
    const float* td_b0 = (const float*)d_in[9];
    const float* td_w1 = (const float*)d_in[10];
    const float* td_b1 = (const float*)d_in[11];
    const float* fc1_w = (const float*)d_in[12];
    const float* fc1_b = (const float*)d_in[13];
    const float* fc2_w = (const float*)d_in[14];
    const float* fc2_b = (const float*)d_in[15];
    float* out = (float*)d_out;

    float* ws  = (float*)d_ws;
    float* x0  = ws;                    // 100352 f
    float* h00 = x0  + BB*HD*SP;
    float* h01 = h00 + BB*HD*SP;
    float* h02 = h01 + BB*HD*SP;
    float* h10 = h02 + BB*HD*SP;
    float* h11 = h10 + BB*HD*SP;
    float* h12 = h11 + BB*HD*SP;
    float* td0 = h12 + BB*HD*SP;        // 200704 f
    float* td1 = td0 + BB*C2*SP;
    float* p1  = td1 + BB*C2*SP;        // 1600 f
    int* flags = (int*)(p1 + BB*100);   // 2 ints

    hipMemsetAsync(flags, 0, 2*sizeof(int), stream);

    input_conv_kernel<<<(BB*HD*SP + 255)/256, 256, 0, stream>>>(input_tensor, icw, icb, x0);

    const float* gw0 = gates_w,            *gw1 = gates_w + C2*C2*9, *gw2 = gates_w + 2*C2*C2*9;
    const float* gb0 = gates_b,            *gb1 = gates_b + C2,      *gb2 = gates_b + 2*C2;
    const float* cw0 = can_w,              *cw1 = can_w + HD*C2*9,   *cw2 = can_w + 2*HD*C2*9;
    const float* cb0 = can_b,              *cb1 = can_b + HD,        *cb2 = can_b + 2*HD;

    // Sweep 0: all three nodes independent (prev state is structurally zero).
    // td for nodes 0/1 is exactly the bias reshape; node 2 uses external topdown.
    GruArgs s0n0 = { x0,      nullptr, nullptr, td_b0, nullptr, gw0, gb0, cw0, cb0, h00, nullptr,  1.0f };
    GruArgs s0n1 = { nullptr, nullptr, nullptr, td_b1, nullptr, gw1, gb1, cw1, cb1, h01, flags+0,  0.8f };
    GruArgs s0n2 = { nullptr, nullptr, topdown, nullptr, nullptr, gw2, gb2, cw2, cb2, h02, flags+1, 0.7f };
    gru_kernel<<<3*BLK_PER_NODE, 256, 0, stream>>>(s0n0, s0n1, s0n2);

    // Sweep-1 td projections; early-exit when sweep-0 states are all-zero.
    td_gemm_kernel<<<2*49, 256, 0, stream>>>(h01, td_w0, td_b0, td0,
                                             h02, td_w1, td_b1, td1, flags);

    // Sweep 1: serial chain (in-sweep aliasing: node k sees node k-1's new state).
    GruArgs s1n0 = { x0,  h00, td0, td_b0, flags+0, gw0, gb0, cw0, cb0, h10, nullptr, 1.0f };
    gru_kernel<<<BLK_PER_NODE, 256, 0, stream>>>(s1n0, s1n0, s1n0);
    GruArgs s1n1 = { h10, h01, td1, td_b1, flags+1, gw1, gb1, cw1, cb1, h11, nullptr, 0.8f };
    gru_kernel<<<BLK_PER_NODE, 256, 0, stream>>>(s1n1, s1n1, s1n1);
    GruArgs s1n2 = { h11, h02, topdown, nullptr, nullptr, gw2, gb2, cw2, cb2, h12, nullptr, 0.7f };
    gru_kernel<<<BLK_PER_NODE, 256, 0, stream>>>(s1n2, s1n2, s1n2);

    fc1_kernel<<<100, 256, 0, stream>>>(h12, fc1_w, fc1_b, p1);
    fc2_kernel<<<1, 256, 0, stream>>>(p1, fc2_w, fc2_b, out);
}

// Round 2
// 312.705 us; speedup vs baseline: 1.0119x; 1.0119x over previous
//
#include <hip/hip_runtime.h>
#include <cstddef>

#define HD 8
#define C2 16
#define HH 28
#define WW 28
#define BB 16
#define SP (HH*WW)           // 784
#define FEAT (HD*SP)         // 6272
#define FEAT2 (C2*SP)        // 12544

#define TILE_ROWS 2
#define NT (HH/TILE_ROWS)    // 14
#define BLK_PER_NODE (BB*NT) // 224

__device__ __forceinline__ float sigf(float x) { return 1.0f / (1.0f + expf(-x)); }

struct GruArgs {
    const float* x;        // (B,8,784) or null (=> zeros)
    const float* h;        // (B,8,784) or null (=> zeros)
    const float* td;       // full (B,16,784) or null
    const float* td_bias;  // (12544) bias-reshape path
    const int*   td_flag;  // if set: *flag==0 -> bias path, else td path
    const float* gw;       // (16,16,3,3)
    const float* gb;       // (16)
    const float* cw;       // (8,16,3,3)
    const float* cb;       // (8)
    float*       hout;     // (B,8,784)
    int*         out_flag; // optional: set to 1 if any output nonzero
    float        xscale;
};

// Fused ConvGRU cell. Block = (node, image, 2-row tile). 256 threads.
__global__ __launch_bounds__(256)
void gru_kernel(GruArgs a0, GruArgs a1, GruArgs a2) {
    const int tid   = threadIdx.x;
    const int node  = blockIdx.x / BLK_PER_NODE;
    const int local = blockIdx.x % BLK_PER_NODE;
    const int bi    = local / NT;
    const int r0    = (local % NT) * TILE_ROWS;

    GruArgs a = a0;
    if (node == 1) a = a1;
    else if (node == 2) a = a2;

    __shared__ float s_gw[C2*C2*9];                 // 2304 f
    __shared__ float s_cw[HD*C2*9];                 // 1152 f
    __shared__ float s_gb[C2];
    __shared__ float s_cb[HD];
    __shared__ float s_comb[C2][TILE_ROWS+4][32];   // rows r0-2..r0+3, cols -2..29
    __shared__ float s_cin[C2][TILE_ROWS+2][32];    // rows r0-1..r0+2, cols -1..28(+pad)

    const bool use_bias = a.td_flag ? (*a.td_flag == 0) : (a.td == nullptr);

    for (int i = tid; i < C2*C2*9; i += 256) s_gw[i] = a.gw[i];
    for (int i = tid; i < HD*C2*9; i += 256) s_cw[i] = a.cw[i];
    if (tid < C2) s_gb[tid] = a.gb[tid];
    if (tid < HD) s_cb[tid] = a.cb[tid];

    // Phase A1: combined = concat([xscale*x, h]) * sigmoid(td), zero-padded tile
    for (int i = tid; i < C2*(TILE_ROWS+4)*32; i += 256) {
        int cidx = i & 31;
        int ridx = (i >> 5) % (TILE_ROWS+4);
        int c    = i / ((TILE_ROWS+4)*32);
        int row = r0 - 2 + ridx;
        int col = cidx - 2;
        float v = 0.0f;
        if (row >= 0 && row < HH && col >= 0 && col < WW) {
            float base = 0.0f;
            if (c < HD) { if (a.x) base = a.xscale * a.x[((size_t)bi*HD + c)*SP + row*WW + col]; }
            else        { if (a.h) base = a.h[((size_t)bi*HD + (c-HD))*SP + row*WW + col]; }
            if (base != 0.0f) {
                float tdv = use_bias ? a.td_bias[c*SP + row*WW + col]
                                     : a.td[((size_t)bi*C2 + c)*SP + row*WW + col];
                v = base * sigf(tdv);
            }
        }
        s_comb[c][ridx][cidx] = v;
    }

    // Phase A2: cand-input channels 0..7 = xscale * x (unmodulated)
    for (int i = tid; i < HD*(TILE_ROWS+2)*32; i += 256) {
        int cidx = i & 31;
        int ridx = (i >> 5) % (TILE_ROWS+2);
        int c    = i / ((TILE_ROWS+2)*32);
        int row = r0 - 1 + ridx;
        int col = cidx - 1;
        float v = 0.0f;
        if (a.x && row >= 0 && row < HH && col >= 0 && col < WW)
            v = a.xscale * a.x[((size_t)bi*HD + c)*SP + row*WW + col];
        s_cin[c][ridx][cidx] = v;
    }

    __syncthreads();

    // Phase B: r gates at rows r0-1..r0+2 (4) x cols -1..28 (30) x 8ch (2 halves)
    if (tid < (TILE_ROWS+2)*30*2) {
        int half  = tid & 1;
        int pos   = tid >> 1;
        int ridx2 = pos / 30;        // 0..3 ; row = r0-1+ridx2
        int cp    = pos % 30;        // col = cp-1
        float acc0 = s_gb[half*4+0], acc1 = s_gb[half*4+1],
              acc2 = s_gb[half*4+2], acc3 = s_gb[half*4+3];
        for (int ic = 0; ic < C2; ++ic) {
            float cv[3][3];
            #pragma unroll
            for (int dy = 0; dy < 3; ++dy)
                #pragma unroll
                for (int dx = 0; dx < 3; ++dx)
                    cv[dy][dx] = s_comb[ic][ridx2+dy][cp+dx];
            const float* wp = &s_gw[(half*4*C2 + ic)*9];
            #pragma unroll
            for (int dy = 0; dy < 3; ++dy)
                #pragma unroll
                for (int dx = 0; dx < 3; ++dx) {
                    float cvv = cv[dy][dx];
                    acc0 += cvv * wp[0*C2*9 + dy*3+dx];
                    acc1 += cvv * wp[1*C2*9 + dy*3+dx];
                    acc2 += cvv * wp[2*C2*9 + dy*3+dx];
                    acc3 += cvv * wp[3*C2*9 + dy*3+dx];
                }
        }
        int row = r0 - 1 + ridx2;
        int col = cp - 1;
        bool inb = (row >= 0 && row < HH && col >= 0 && col < WW);
        float av[4] = {acc0, acc1, acc2, acc3};
        #pragma unroll
        for (int o = 0; o < 4; ++o) {
            int ch = half*4 + o;
            float hv = 0.0f;
            if (a.h && inb) hv = a.h[((size_t)bi*HD + ch)*SP + row*WW + col];
            s_cin[HD + ch][ridx2][cp] = sigf(av[o]) * hv;
        }
    }

    __syncthreads();

    // Phase C: u gate + cand conv + blend, 2 rows x 28 cols x 8 ch
    bool nz = false;
    for (int item = tid; item < TILE_ROWS*WW*HD; item += 256) {
        int c   = item / (TILE_ROWS*WW);
        int rem = item % (TILE_ROWS*WW);
        int rr  = rem / WW;
        int col = rem % WW;
        float uacc = s_gb[HD + c];
        float cacc = s_cb[c];
        for (int ic = 0; ic < C2; ++ic) {
            const float* uwp = &s_gw[((HD + c)*C2 + ic)*9];
            const float* cwp = &s_cw[(c*C2 + ic)*9];
            #pragma unroll
            for (int dy = 0; dy < 3; ++dy)
                #pragma unroll
                for (int dx = 0; dx < 3; ++dx) {
                    uacc += s_comb[ic][rr+1+dy][col+1+dx] * uwp[dy*3+dx];
                    cacc += s_cin[ic][rr+dy][col+dx]      * cwp[dy*3+dx];
                }
        }
        float u    = sigf(uacc);
        float cand = tanhf(cacc);
        int row = r0 + rr;
        size_t oidx = ((size_t)bi*HD + c)*SP + row*WW + col;
        float hv = a.h ? a.h[oidx] : 0.0f;
        float outv = (1.0f - u) * hv + u * cand;
        a.hout[oidx] = outv;
        nz |= (outv != 0.0f);
    }

    if (a.out_flag) {
        unsigned long long m = __ballot(nz);
        if ((tid & 63) == 0 && m) atomicOr(a.out_flag, 1);
    }
}

__global__ __launch_bounds__(256)
void input_conv_kernel(const float* __restrict__ in, const float* __restrict__ w,
                       const float* __restrict__ b, float* __restrict__ out,
                       int* __restrict__ flags) {
    int idx = blockIdx.x * blockDim.x + threadIdx.x;   // over B*8*784
    if (idx == 0) { flags[0] = 0; flags[1] = 0; }      // replaces hipMemsetAsync
    if (idx >= BB*HD*SP) return;
    int col = idx % WW;
    int row = (idx / WW) % HH;
    int oc  = (idx / SP) % HD;
    int bi  = idx / (HD*SP);
    float acc = b[oc];
    for (int c = 0; c < 3; ++c)
        #pragma unroll
        for (int dy = 0; dy < 3; ++dy) {
            int rr = row + dy - 1;
            if (rr < 0 || rr >= HH) continue;
            #pragma unroll
            for (int dx = 0; dx < 3; ++dx) {
                int cc = col + dx - 1;
                if (cc < 0 || cc >= WW) continue;
                acc += in[((size_t)bi*3 + c)*SP + rr*WW + cc] * w[((oc*3 + c)*3 + dy)*3 + dx];
            }
        }
    out[idx] = acc;
}

// Flag-gated dual td projection: out[b,:] = bias + (scale*hin[b,:]) @ w^T
// Skipped entirely (consumer uses bias path) when the input tensor is all-zero.
__global__ __launch_bounds__(256)
void td_gemm_kernel(const float* __restrict__ h1, const float* __restrict__ w0,
                    const float* __restrict__ b0, float* __restrict__ out0,
                    const float* __restrict__ h2, const float* __restrict__ w1,
                    const float* __restrict__ b1, float* __restrict__ out1,
                    const int* __restrict__ flags) {
    int node = blockIdx.x / 49;
    if (flags[node] == 0) return;
    int j = (blockIdx.x % 49) * 256 + threadIdx.x;
    if (j >= FEAT2) return;
    const float* hin  = node ? h2 : h1;
    const float* w    = node ? w1 : w0;
    const float* bias = node ? b1 : b0;
    float* out        = node ? out1 : out0;
    float scale       = node ? 0.5f : 0.6f;
    float acc[BB];
    #pragma unroll
    for (int q = 0; q < BB; ++q) acc[q] = 0.0f;
    const float* wr = w + (size_t)j * FEAT;
    for (int k = 0; k < FEAT; ++k) {
        float wv = wr[k];
        #pragma unroll
        for (int q = 0; q < BB; ++q) acc[q] += (scale * hin[(size_t)q*FEAT + k]) * wv;
    }
    #pragma unroll
    for (int q = 0; q < BB; ++q) out[(size_t)q*FEAT2 + j] = acc[q] + bias[j];
}

__global__ __launch_bounds__(256)
void fc1_kernel(const float* __restrict__ in, const float* __restrict__ w,
                const float* __restrict__ b, float* __restrict__ out) {
    int j    = blockIdx.x;          // 0..99
    int wave = threadIdx.x >> 6;    // 0..3, each handles 4 batch rows
    int lane = threadIdx.x & 63;
    float acc[4] = {0.f, 0.f, 0.f, 0.f};
    const float* wr = w + (size_t)j * FEAT;
    for (int k = lane; k < FEAT; k += 64) {
        float wv = wr[k];
        #pragma unroll
        for (int q = 0; q < 4; ++q) {
            float v = in[(size_t)(wave*4+q)*FEAT + k];
            acc[q] += fmaxf(v, 0.0f) * wv;
        }
    }
    #pragma unroll
    for (int off = 32; off > 0; off >>= 1)
        #pragma unroll
        for (int q = 0; q < 4; ++q)
            acc[q] += __shfl_down(acc[q], off);
    if (lane == 0) {
        #pragma unroll
        for (int q = 0; q < 4; ++q)
            out[(size_t)(wave*4+q)*100 + j] = acc[q] + b[j];
    }
}

__global__ __launch_bounds__(256)
void fc2_kernel(const float* __restrict__ p1, const float* __restrict__ w,
                const float* __restrict__ b, float* __restrict__ out) {
    int t = threadIdx.x;
    if (t >= BB*10) return;
    int bi = t / 10, j = t % 10;
    float acc = b[j];
    for (int k = 0; k < 100; ++k)
        acc += fmaxf(p1[bi*100 + k], 0.0f) * w[j*100 + k];
    out[bi*10 + j] = acc;
}

extern "C" void kernel_launch(void* const* d_in, const int* in_sizes, int n_in,
                              void* d_out, int out_size, void* d_ws, size_t ws_size,
                              hipStream_t stream) {
    const float* input_tensor = (const float*)d_in[0];
    const float* topdown      = (const float*)d_in[1];
    const float* icw  = (const float*)d_in[2];
    const float* icb  = (const float*)d_in[3];
    const float* gates_w = (const float*)d_in[4];
    const float* gates_b = (const float*)d_in[5];
    const float* can_w   = (const float*)d_in[6];
    const float* can_b   = (const float*)d_in[7];
    const float* td_w0 = (const float*)d_in[8];
    const float* td_b0 = (const float*)d_in[9];
    const float* td_w1 = (const float*)d_in[10];
    const float* td_b1 = (const float*)d_in[11];
    const float* fc1_w = (const float*)d_in[12];
    const float* fc1_b = (const float*)d_in[13];
    const float* fc2_w = (const float*)d_in[14];
    const float* fc2_b = (const float*)d_in[15];
    float* out = (float*)d_out;

    float* ws  = (float*)d_ws;
    float* x0  = ws;                    // 100352 f
    float* h00 = x0  + BB*HD*SP;
    float* h01 = h00 + BB*HD*SP;
    float* h02 = h01 + BB*HD*SP;
    float* h10 = h02 + BB*HD*SP;
    float* h11 = h10 + BB*HD*SP;
    float* h12 = h11 + BB*HD*SP;
    float* td0 = h12 + BB*HD*SP;        // 200704 f
    float* td1 = td0 + BB*C2*SP;
    float* p1  = td1 + BB*C2*SP;        // 1600 f
    int* flags = (int*)(p1 + BB*100);   // 2 ints

    input_conv_kernel<<<(BB*HD*SP + 255)/256, 256, 0, stream>>>(input_tensor, icw, icb, x0, flags);

    const float* gw0 = gates_w,            *gw1 = gates_w + C2*C2*9, *gw2 = gates_w + 2*C2*C2*9;
    const float* gb0 = gates_b,            *gb1 = gates_b + C2,      *gb2 = gates_b + 2*C2;
    const float* cw0 = can_w,              *cw1 = can_w + HD*C2*9,   *cw2 = can_w + 2*HD*C2*9;
    const float* cb0 = can_b,              *cb1 = can_b + HD,        *cb2 = can_b + 2*HD;

    // Sweep 0: all three nodes independent (prev state is structurally zero).
    // td for nodes 0/1 is exactly the bias reshape; node 2 uses external topdown.
    GruArgs s0n0 = { x0,      nullptr, nullptr, td_b0, nullptr, gw0, gb0, cw0, cb0, h00, nullptr,  1.0f };
    GruArgs s0n1 = { nullptr, nullptr, nullptr, td_b1, nullptr, gw1, gb1, cw1, cb1, h01, flags+0,  0.8f };
    GruArgs s0n2 = { nullptr, nullptr, topdown, nullptr, nullptr, gw2, gb2, cw2, cb2, h02, flags+1, 0.7f };
    gru_kernel<<<3*BLK_PER_NODE, 256, 0, stream>>>(s0n0, s0n1, s0n2);

    // Sweep-1 td projections; early-exit when sweep-0 states are all-zero.
    td_gemm_kernel<<<2*49, 256, 0, stream>>>(h01, td_w0, td_b0, td0,
                                             h02, td_w1, td_b1, td1, flags);

    // Sweep 1: serial chain (in-sweep aliasing: node k sees node k-1's new state).
    GruArgs s1n0 = { x0,  h00, td0, td_b0, flags+0, gw0, gb0, cw0, cb0, h10, nullptr, 1.0f };
    gru_kernel<<<BLK_PER_NODE, 256, 0, stream>>>(s1n0, s1n0, s1n0);
    GruArgs s1n1 = { h10, h01, td1, td_b1, flags+1, gw1, gb1, cw1, cb1, h11, nullptr, 0.8f };
    gru_kernel<<<BLK_PER_NODE, 256, 0, stream>>>(s1n1, s1n1, s1n1);
    GruArgs s1n2 = { h11, h02, topdown, nullptr, nullptr, gw2, gb2, cw2, cb2, h12, nullptr, 0.7f };
    gru_kernel<<<BLK_PER_NODE, 256, 0, stream>>>(s1n2, s1n2, s1n2);

    fc1_kernel<<<100, 256, 0, stream>>>(h12, fc1_w, fc1_b, p1);
    fc2_kernel<<<1, 256, 0, stream>>>(p1, fc2_w, fc2_b, out);
}